// Round 7
// baseline (346.404 us; speedup 1.0000x reference)
//
#include <hip/hip_runtime.h>
#include <hip/hip_bf16.h>
#include <math.h>

#define N_USERS 100000
#define N_ITEMS 50000
#define N_EDGES 2000000
#define D 64

// Coarse bins: 512 nodes per bin (binfill write-coalescing granularity).
#define FB_BINS 98                    // ceil(50000/512)  forward (by item)
#define BB_BINS 196                   // ceil(100000/512) backward (by user)
#define NBINS   (FB_BINS + BB_BINS)   // 294
#define CHUNK   4096                  // edges per binfill WG (112B avg runs)
#define NCHUNK  ((N_EDGES + CHUNK - 1) / CHUNK)   // 489
// fwd fine space: (item, shard), shard = (user >= 50000) -> 2 slots per item.
#define FOFF_F_N (FB_BINS * 1024 + 1) // 100353
#define FOFF_B_N (BB_BINS * 512 + 1)  // 100353
#define TOTSLOT  (2 * N_EDGES)
// gathers: 256-thr WGs, 4 waves, 4 nodes per wave = 16 nodes per WG.
#define FWD_WGS (N_ITEMS / 16)        // 3125
#define BWD_WGS ((N_USERS + 15) / 16) // 6250
#define SHARD_SPLIT 50000             // user id threshold: 6.4MB / 6.4MB halves

// ---- bf16 pack/unpack helpers --------------------------------------------
__device__ __forceinline__ float blo(unsigned u) {
    union { unsigned i; float f; } c; c.i = u << 16; return c.f;
}
__device__ __forceinline__ float bhi(unsigned u) {
    union { unsigned i; float f; } c; c.i = u & 0xFFFF0000u; return c.f;
}
__device__ __forceinline__ unsigned bpack(float x, float y) {
    __hip_bfloat16 a = __float2bfloat16(x), b = __float2bfloat16(y);
    unsigned short ua = *reinterpret_cast<unsigned short*>(&a);
    unsigned short ub = *reinterpret_cast<unsigned short*>(&b);
    return (unsigned)ua | ((unsigned)ub << 16);
}

// ---------------------------------------------------------------------------
// gather_run: accumulate bf16 rows tbl[idx*32+q] for idx in stage2[a..b),
// half-wave per edge, 16/8/2/1 unroll ladder (8 rows in flight per lane).
// ---------------------------------------------------------------------------
__device__ __forceinline__ void gather_run(
    const unsigned* __restrict__ tbl, const unsigned* __restrict__ stage2,
    int a, int b, int q, int half, float& ax, float& ay) {
    int k = a;
    for (; k + 16 <= b; k += 16) {
        int s0 = (int)__builtin_nontemporal_load(&stage2[k + half]);
        int s1 = (int)__builtin_nontemporal_load(&stage2[k + 2 + half]);
        int s2 = (int)__builtin_nontemporal_load(&stage2[k + 4 + half]);
        int s3 = (int)__builtin_nontemporal_load(&stage2[k + 6 + half]);
        int s4 = (int)__builtin_nontemporal_load(&stage2[k + 8 + half]);
        int s5 = (int)__builtin_nontemporal_load(&stage2[k + 10 + half]);
        int s6 = (int)__builtin_nontemporal_load(&stage2[k + 12 + half]);
        int s7 = (int)__builtin_nontemporal_load(&stage2[k + 14 + half]);
        unsigned u0 = tbl[(s0 << 5) + q];
        unsigned u1 = tbl[(s1 << 5) + q];
        unsigned u2 = tbl[(s2 << 5) + q];
        unsigned u3 = tbl[(s3 << 5) + q];
        unsigned u4 = tbl[(s4 << 5) + q];
        unsigned u5 = tbl[(s5 << 5) + q];
        unsigned u6 = tbl[(s6 << 5) + q];
        unsigned u7 = tbl[(s7 << 5) + q];
        ax += ((blo(u0) + blo(u1)) + (blo(u2) + blo(u3)))
            + ((blo(u4) + blo(u5)) + (blo(u6) + blo(u7)));
        ay += ((bhi(u0) + bhi(u1)) + (bhi(u2) + bhi(u3)))
            + ((bhi(u4) + bhi(u5)) + (bhi(u6) + bhi(u7)));
    }
    if (k + 8 <= b) {
        int s0 = (int)__builtin_nontemporal_load(&stage2[k + half]);
        int s1 = (int)__builtin_nontemporal_load(&stage2[k + 2 + half]);
        int s2 = (int)__builtin_nontemporal_load(&stage2[k + 4 + half]);
        int s3 = (int)__builtin_nontemporal_load(&stage2[k + 6 + half]);
        unsigned u0 = tbl[(s0 << 5) + q];
        unsigned u1 = tbl[(s1 << 5) + q];
        unsigned u2 = tbl[(s2 << 5) + q];
        unsigned u3 = tbl[(s3 << 5) + q];
        ax += (blo(u0) + blo(u1)) + (blo(u2) + blo(u3));
        ay += (bhi(u0) + bhi(u1)) + (bhi(u2) + bhi(u3));
        k += 8;
    }
    for (; k + 2 <= b; k += 2) {
        unsigned u = tbl[((int)__builtin_nontemporal_load(&stage2[k + half]) << 5) + q];
        ax += blo(u); ay += bhi(u);
    }
    if (k < b && half == 0) {
        unsigned u = tbl[((int)__builtin_nontemporal_load(&stage2[k]) << 5) + q];
        ax += blo(u); ay += bhi(u);
    }
}

// ---------------------------------------------------------------------------
// prep: fused h2b (fp32 -> packed bf16 pairs) + coarse LDS histogram.
// ---------------------------------------------------------------------------
__global__ __launch_bounds__(256) void prep_kernel(
    const float2* __restrict__ hin, unsigned* __restrict__ hu16,
    const int* __restrict__ src, const int* __restrict__ dst,
    int* __restrict__ gh) {
    __shared__ int h[NBINS];
    for (int i = threadIdx.x; i < NBINS; i += 256) h[i] = 0;
    __syncthreads();
    int stride = gridDim.x * blockDim.x;
    int t0 = blockIdx.x * blockDim.x + threadIdx.x;
    for (int i = t0; i < N_USERS * 32; i += stride) {
        float2 v = hin[i];
        hu16[i] = bpack(v.x, v.y);
    }
    for (int e = t0; e < N_EDGES; e += stride) {
        atomicAdd(&h[dst[e] >> 9], 1);
        atomicAdd(&h[FB_BINS + (src[e] >> 9)], 1);
    }
    __syncthreads();
    for (int i = threadIdx.x; i < NBINS; i += 256) {
        int v = h[i];
        if (v) atomicAdd(&gh[i], v);
    }
}

// ---------------------------------------------------------------------------
// scan_soft: block 0 = exclusive scan of 294 coarse bins (-> binoff, gcur);
// block 1 = softmax stats over edge_w (stats[0]=max, stats[1]=sum exp).
// ---------------------------------------------------------------------------
__global__ void scan_soft_kernel(const int* __restrict__ in, int* __restrict__ out,
                                 int* __restrict__ cur,
                                 const float* __restrict__ w, float* __restrict__ stats) {
    __shared__ float redf[16];
    __shared__ int wsum[16];
    int tid = threadIdx.x, lane = tid & 63, wid = tid >> 6;

    if (blockIdx.x == 0) {
        int idx0 = tid * 4;
        int v[4]; int tot = 0;
#pragma unroll
        for (int e = 0; e < 4; e++) {
            int i = idx0 + e;
            v[e] = (i < NBINS) ? in[i] : 0;
            tot += v[e];
        }
        int incl = tot;
#pragma unroll
        for (int off = 1; off < 64; off <<= 1) {
            int t = __shfl_up(incl, off);
            if (lane >= off) incl += t;
        }
        if (lane == 63) wsum[wid] = incl;
        __syncthreads();
        if (wid == 0 && lane < 16) {
            int t = wsum[lane];
            int sc = t;
#pragma unroll
            for (int off = 1; off < 16; off <<= 1) {
                int u = __shfl_up(sc, off);
                if (lane >= off) sc += u;
            }
            wsum[lane] = sc - t;
        }
        __syncthreads();
        int excl = wsum[wid] + incl - tot;
#pragma unroll
        for (int e = 0; e < 4; e++) {
            int i = idx0 + e;
            if (i < NBINS) { out[i] = excl; cur[i] = excl; }
            if (i == NBINS) out[i] = excl;
            excl += v[e];
        }
        return;
    }

    float m = -INFINITY;
    for (int i = tid; i < N_ITEMS; i += 1024) m = fmaxf(m, w[i]);
#pragma unroll
    for (int off = 32; off; off >>= 1) m = fmaxf(m, __shfl_xor(m, off));
    if (lane == 0) redf[wid] = m;
    __syncthreads();
    if (tid == 0) {
        float t = redf[0];
        for (int k = 1; k < 16; k++) t = fmaxf(t, redf[k]);
        redf[0] = t;
    }
    __syncthreads();
    m = redf[0];
    __syncthreads();

    float s = 0.f;
    for (int i = tid; i < N_ITEMS; i += 1024) s += expf(w[i] - m);
#pragma unroll
    for (int off = 32; off; off >>= 1) s += __shfl_xor(s, off);
    if (lane == 0) redf[wid] = s;
    __syncthreads();
    if (tid == 0) {
        float t = 0.f;
        for (int k = 0; k < 16; k++) t += redf[k];
        stats[0] = m;
        stats[1] = t;
    }
}

// ---------------------------------------------------------------------------
// binfill: chunk-aggregated scatter into coarse bins (dense runs, L2-merged).
// fwd entry: s(17b) | d_local9<<17 ; bwd entry: d(16b) | s_local9<<16.
// ---------------------------------------------------------------------------
__global__ __launch_bounds__(256) void binfill_kernel(
    const int* __restrict__ src, const int* __restrict__ dst,
    int* __restrict__ gcur, unsigned* __restrict__ stage) {
    __shared__ int cnt[NBINS];
    __shared__ int gbase[NBINS];
    __shared__ int lcur[NBINS];
    int c = blockIdx.x;
    int base = c * CHUNK;
    int nEdge = N_EDGES - base; if (nEdge > CHUNK) nEdge = CHUNK;

    for (int t = threadIdx.x; t < NBINS; t += 256) { cnt[t] = 0; lcur[t] = 0; }
    __syncthreads();

    int es[16], ed[16];
#pragma unroll
    for (int j = 0; j < 16; j++) {
        int k = j * 256 + threadIdx.x;
        if (k < nEdge) {
            es[j] = src[base + k];
            ed[j] = dst[base + k];
            atomicAdd(&cnt[ed[j] >> 9], 1);
            atomicAdd(&cnt[FB_BINS + (es[j] >> 9)], 1);
        } else {
            es[j] = -1;
        }
    }
    __syncthreads();
    for (int t = threadIdx.x; t < NBINS; t += 256) {
        int cv = cnt[t];
        gbase[t] = cv ? atomicAdd(&gcur[t], cv) : 0;
    }
    __syncthreads();
#pragma unroll
    for (int j = 0; j < 16; j++) {
        if (es[j] >= 0) {
            int s = es[j], d = ed[j];
            int bf = d >> 9;
            int p = atomicAdd(&lcur[bf], 1);
            stage[gbase[bf] + p] = (unsigned)s | ((unsigned)(d & 511) << 17);
            int bb = FB_BINS + (s >> 9);
            int q = atomicAdd(&lcur[bb], 1);
            stage[gbase[bb] + q] = (unsigned)d | ((unsigned)(s & 511) << 16);
        }
    }
}

// ---------------------------------------------------------------------------
// redist3: balanced fine counting-sort, 196 WGs (one CU round), all-LDS.
// WG 0..97: one fwd bin, fine key = (item_local<<1)|shard, shard=(user>=50000).
// WG 98..195: two bwd bins sequentially, fine key = user_local.
// stage2 payload = bare gather index.
// ---------------------------------------------------------------------------
__global__ __launch_bounds__(512) void redist3_kernel(
    const unsigned* __restrict__ stage, const int* __restrict__ binoff,
    unsigned* __restrict__ stage2, int* __restrict__ foff_f, int* __restrict__ foff_b) {
    __shared__ int cnt[1024];
    __shared__ int wsum[8];
    int wg = blockIdx.x, t = threadIdx.x, lane = t & 63, wv = t >> 6;

    if (wg < FB_BINS) {
        int B = wg;
        int beg = binoff[B], end = binoff[B + 1];
        cnt[t] = 0; cnt[t + 512] = 0;
        __syncthreads();
        for (int k = beg + t; k < end; k += 512) {
            unsigned e = stage[k];
            int key = (int)((e >> 17) & 511) << 1;
            key |= ((e & 0x1FFFFu) >= SHARD_SPLIT) ? 1 : 0;
            atomicAdd(&cnt[key], 1);
        }
        __syncthreads();
        int c0 = cnt[t << 1], c1 = cnt[(t << 1) | 1];
        int v = c0 + c1;
        int incl = v;
#pragma unroll
        for (int off = 1; off < 64; off <<= 1) {
            int u = __shfl_up(incl, off);
            if (lane >= off) incl += u;
        }
        if (lane == 63) wsum[wv] = incl;
        __syncthreads();
        if (t == 0) {
            int run = 0;
#pragma unroll
            for (int k2 = 0; k2 < 8; k2++) { int x = wsum[k2]; wsum[k2] = run; run += x; }
        }
        __syncthreads();
        int base = beg + wsum[wv] + incl - v;
        int slot = (B << 10) | (t << 1);
        foff_f[slot] = base;
        foff_f[slot | 1] = base + c0;
        cnt[t << 1] = base;
        cnt[(t << 1) | 1] = base + c0;
        if (B == FB_BINS - 1 && t == 0) foff_f[FB_BINS * 1024] = end;
        __syncthreads();
        for (int k = beg + t; k < end; k += 512) {
            unsigned e = stage[k];
            int key = (int)((e >> 17) & 511) << 1;
            key |= ((e & 0x1FFFFu) >= SHARD_SPLIT) ? 1 : 0;
            int p = atomicAdd(&cnt[key], 1);
            stage2[p] = e & 0x1FFFFu;
        }
    } else {
        for (int pass = 0; pass < 2; pass++) {
            int B = FB_BINS + ((wg - FB_BINS) << 1) + pass;
            int beg = binoff[B], end = binoff[B + 1];
            cnt[t] = 0;
            __syncthreads();
            for (int k = beg + t; k < end; k += 512) {
                unsigned e = stage[k];
                atomicAdd(&cnt[(e >> 16) & 511], 1);
            }
            __syncthreads();
            int v = cnt[t];
            int incl = v;
#pragma unroll
            for (int off = 1; off < 64; off <<= 1) {
                int u = __shfl_up(incl, off);
                if (lane >= off) incl += u;
            }
            if (lane == 63) wsum[wv] = incl;
            __syncthreads();
            if (t == 0) {
                int run = 0;
#pragma unroll
                for (int k2 = 0; k2 < 8; k2++) { int x = wsum[k2]; wsum[k2] = run; run += x; }
            }
            __syncthreads();
            int base = beg + wsum[wv] + incl - v;
            foff_b[((B - FB_BINS) << 9) | t] = base;
            cnt[t] = base;
            if (B == NBINS - 1 && t == 0) foff_b[BB_BINS * 512] = end;
            __syncthreads();
            for (int k = beg + t; k < end; k += 512) {
                unsigned e = stage[k];
                int p = atomicAdd(&cnt[(e >> 16) & 511], 1);
                stage2[p] = e & 0xFFFFu;
            }
            __syncthreads();
        }
    }
}

// ---------------------------------------------------------------------------
// fwd_s0: gather shard-0 edges (user < 50000 -> 6.4MB hu16 window, the ONLY
// table window touched during this launch => L2-resident chip-wide, no
// pinning needed). fp32 partials to pacc (nontemporal scalar pair: don't
// evict window).
// ---------------------------------------------------------------------------
__global__ __launch_bounds__(256) void fwd_s0_kernel(
    const unsigned* __restrict__ hu16, const unsigned* __restrict__ stage2,
    const int* __restrict__ foff_f, float* __restrict__ pacc) {
    int tid = threadIdx.x, lane = tid & 63, wv = tid >> 6;
    int q = lane & 31, half = lane >> 5;
    int i0 = blockIdx.x * 16;

    for (int il = wv; il < 16; il += 4) {
        int i = i0 + il;
        if (i >= N_ITEMS) break;
        int a = foff_f[i << 1], b = foff_f[(i << 1) | 1];
        float ax = 0.f, ay = 0.f;
        gather_run(hu16, stage2, a, b, q, half, ax, ay);
        ax += __shfl_xor(ax, 32);
        ay += __shfl_xor(ay, 32);
        if (half == 0) {
            size_t off = ((size_t)i * 32 + q) * 2;
            __builtin_nontemporal_store(ax, &pacc[off]);
            __builtin_nontemporal_store(ay, &pacc[off + 1]);
        }
    }
}

// ---------------------------------------------------------------------------
// fwd_s1: gather shard-1 edges (user >= 50000 -> other 6.4MB window), add
// pacc partial, fused epilogue -> bf16 rst.
// ---------------------------------------------------------------------------
__global__ __launch_bounds__(256) void fwd_s1_kernel(
    const unsigned* __restrict__ hu16, const float* __restrict__ pf,
    const float* __restrict__ edge_w, const unsigned* __restrict__ stage2,
    const int* __restrict__ foff_f, const float* __restrict__ stats,
    const float* __restrict__ pacc, unsigned* __restrict__ rst16) {
    int tid = threadIdx.x, lane = tid & 63, wv = tid >> 6;
    int q = lane & 31, half = lane >> 5;
    float m = stats[0], ssum = stats[1];
    const float2* PF2 = (const float2*)pf;
    int i0 = blockIdx.x * 16;

    for (int il = wv; il < 16; il += 4) {
        int i = i0 + il;
        if (i >= N_ITEMS) break;
        int a = foff_f[(i << 1) | 1], b = foff_f[(i << 1) + 2];
        int a0 = foff_f[i << 1];
        float ax = 0.f, ay = 0.f;
        gather_run(hu16, stage2, a, b, q, half, ax, ay);
        ax += __shfl_xor(ax, 32);
        ay += __shfl_xor(ay, 32);
        if (half == 0) {
            size_t off = ((size_t)i * 32 + q) * 2;
            float px = __builtin_nontemporal_load(&pacc[off]);
            float py = __builtin_nontemporal_load(&pacc[off + 1]);
            ax += px; ay += py;
            float deg = (float)(b - a0);
            if (deg < 1.f) deg = 1.f;
            float sc = expf(edge_w[i] - m) / (ssum * deg);
            float2 pv = PF2[(size_t)i * 32 + q];
            float vx = (ax + 0.5f * tanhf(pv.x)) * sc;
            float vy = (ay + 0.5f * tanhf(pv.y)) * sc;
            rst16[(size_t)i * 32 + q] = bpack(vx, vy);
        }
    }
}

// ---------------------------------------------------------------------------
// bwd_gather: pure gather over bf16 rst (6.4MB table); fp32 out with deg norm.
// ---------------------------------------------------------------------------
__global__ __launch_bounds__(256) void bwd_gather_kernel(
    const unsigned* __restrict__ rst16, const unsigned* __restrict__ stage2,
    const int* __restrict__ foff_b, float* __restrict__ out) {
    int tid = threadIdx.x, lane = tid & 63, wv = tid >> 6;
    int q = lane & 31, half = lane >> 5;
    float2* OUT2 = (float2*)out;
    int u0i = blockIdx.x * 16;

    for (int il = wv; il < 16; il += 4) {
        int u = u0i + il;
        if (u >= N_USERS) break;
        int a = foff_b[u], b = foff_b[u + 1];
        float ax = 0.f, ay = 0.f;
        gather_run(rst16, stage2, a, b, q, half, ax, ay);
        ax += __shfl_xor(ax, 32);
        ay += __shfl_xor(ay, 32);
        if (half == 0) {
            float deg = (float)(b - a);
            if (deg < 1.f) deg = 1.f;
            OUT2[(size_t)u * 32 + q] = make_float2(ax / deg, ay / deg);
        }
    }
}

// ---------------------------------------------------------------------------
extern "C" void kernel_launch(void* const* d_in, const int* in_sizes, int n_in,
                              void* d_out, int out_size, void* d_ws, size_t ws_size,
                              hipStream_t stream) {
    const float* h_user = (const float*)d_in[0];   // [N_USERS, D]
    const float* pf     = (const float*)d_in[1];   // [N_ITEMS, D]
    const float* edge_w = (const float*)d_in[2];   // [N_ITEMS]
    const int*   src    = (const int*)d_in[3];     // [N_EDGES]
    const int*   dst    = (const int*)d_in[4];     // [N_EDGES]
    float* out = (float*)d_out;                    // [N_USERS, D]

    // workspace carve-up (~65 MB)
    char* p = (char*)d_ws;
    int* gh      = (int*)p;     p += sizeof(int) * NBINS;
    int* binoff  = (int*)p;     p += sizeof(int) * (NBINS + 1);
    int* gcur    = (int*)p;     p += sizeof(int) * NBINS;
    int* foff_f  = (int*)p;     p += sizeof(int) * FOFF_F_N;
    int* foff_b  = (int*)p;     p += sizeof(int) * FOFF_B_N;
    float* stats = (float*)p;   p += 4 * sizeof(float);
    unsigned* stage  = (unsigned*)p; p += sizeof(unsigned) * (size_t)TOTSLOT;
    unsigned* stage2 = (unsigned*)p; p += sizeof(unsigned) * (size_t)TOTSLOT;
    unsigned* hu16   = (unsigned*)p; p += sizeof(unsigned) * (size_t)N_USERS * 32;
    unsigned* rst16  = (unsigned*)p; p += sizeof(unsigned) * (size_t)N_ITEMS * 32;
    float* pacc      = (float*)p;    p += sizeof(float) * (size_t)N_ITEMS * 64;

    hipMemsetAsync(gh, 0, sizeof(int) * NBINS, stream);

    prep_kernel<<<1024, 256, 0, stream>>>((const float2*)h_user, hu16, src, dst, gh);
    scan_soft_kernel<<<2, 1024, 0, stream>>>(gh, binoff, gcur, edge_w, stats);
    binfill_kernel<<<NCHUNK, 256, 0, stream>>>(src, dst, gcur, stage);
    redist3_kernel<<<196, 512, 0, stream>>>(stage, binoff, stage2, foff_f, foff_b);
    fwd_s0_kernel<<<FWD_WGS, 256, 0, stream>>>(hu16, stage2, foff_f, pacc);
    fwd_s1_kernel<<<FWD_WGS, 256, 0, stream>>>(hu16, pf, edge_w, stage2, foff_f, stats, pacc, rst16);
    bwd_gather_kernel<<<BWD_WGS, 256, 0, stream>>>(rst16, stage2, foff_b, out);
}